// Round 7
// baseline (3525.447 us; speedup 1.0000x reference)
//
#include <hip/hip_runtime.h>
#include <hip/hip_bf16.h>
#include <math.h>

// Problem dims
#define L_   16
#define N_   2048
#define C_   8
#define D_   64
#define H_   256
#define HID_ 256
#define F_   527
#define LN_  (L_*N_)   // 32768

typedef __attribute__((ext_vector_type(8))) short s8v;   // 8 bf16 = 4 VGPR
typedef __attribute__((ext_vector_type(4))) float f4v;   // MFMA 16x16 accumulator

__device__ __forceinline__ float sigf(float x) { return 1.f / (1.f + expf(-x)); }

// float -> bf16 bits, round-to-nearest-even (avoids header API differences)
__device__ __forceinline__ short f2bf(float f) {
  unsigned u = __float_as_uint(f);
  unsigned r = (u + 0x7fffu + ((u >> 16) & 1u)) >> 16;
  return (short)(r & 0xffffu);
}

__device__ __forceinline__ void fma_gates(float4& a, float4 xv,
                                          float4 w0, float4 w1, float4 w2, float4 w3) {
  a.x = fmaf(xv.x, w0.x, fmaf(xv.y, w1.x, fmaf(xv.z, w2.x, fmaf(xv.w, w3.x, a.x))));
  a.y = fmaf(xv.x, w0.y, fmaf(xv.y, w1.y, fmaf(xv.z, w2.y, fmaf(xv.w, w3.y, a.y))));
  a.z = fmaf(xv.x, w0.z, fmaf(xv.y, w1.z, fmaf(xv.z, w2.z, fmaf(xv.w, w3.z, a.z))));
  a.w = fmaf(xv.x, w0.w, fmaf(xv.y, w1.w, fmaf(xv.z, w2.w, fmaf(xv.w, w3.w, a.w))));
}

// ---------- weight pre-transposes ----------
// W [1024][K] -> out [K][256][4]  (gate-interleaved: out[k][u][j] = W[j*256+u][k])
__global__ void k_tr_gates(const float* __restrict__ W, float* __restrict__ out, int K) {
  int idx = blockIdx.x * 256 + threadIdx.x;
  if (idx >= K * 1024) return;
  int k = idx >> 10, r = idx & 1023;
  int u = r >> 2, j = r & 3;
  out[idx] = W[(size_t)(j * 256 + u) * K + k];
}

// W [256][Cn] -> out [Cn][256]
__global__ void k_tr_plain(const float* __restrict__ W, float* __restrict__ out, int Cn) {
  int idx = blockIdx.x * 256 + threadIdx.x;
  if (idx >= 256 * Cn) return;
  int c = idx >> 8, r = idx & 255;
  out[idx] = W[(size_t)r * Cn + c];
}

// W [1024][K] fp32 -> bf16 MFMA-fragment-packed:
// out[((kc*1024 + n)*4 + kg)*8 + j] = bf16(W[n][kc*32 + kg*8 + j])
// so B-frag for col-tile ct, k-chunk kc is one coalesced 16B/lane load:
// lane l reads 8 shorts at ((kc*1024 + ct*16 + (l&15))*4 + (l>>4))*8.
__global__ void k_pack_gates(const float* __restrict__ W, short* __restrict__ out, int K) {
  int idx = blockIdx.x * 256 + threadIdx.x;
  if (idx >= 1024 * K) return;
  int j  = idx & 7;
  int kg = (idx >> 3) & 3;
  int n  = (idx >> 5) & 1023;
  int kc = idx >> 15;
  int k  = kc * 32 + kg * 8 + j;
  out[idx] = f2bf(W[(size_t)n * K + k]);
}

// ---------- lstm1 via MFMA (bf16 in, fp32 acc) ----------
// 8-step LSTM over [32768, 8, 64] x2 inputs, shared weights.
// grid 1024: blocks [0,512) -> cond1, [512,1024) -> cond2. 64 rows/block, 8 waves.
// Wave w owns 4 row-tiles x 8 col-tiles (ct = w + 8q); q = gate*2 + ug, so all 4
// gates of units u = 16w + 128*ug + (lane&15) are wave-local -> register cell update.
// A-frag (x,h) from LDS; B-frag (weights) direct from L2 (pre-packed, coalesced).
// C/D layout per m89/m91: col = lane&15, row = (lane>>4)*4 + reg.
//
// __launch_bounds__(512, 1): EMPIRICAL (rounds 2 & 6) — with 512-thr blocks,
// 2nd arg 2 (and default) caps VGPRs at 128 on this toolchain (acts like CUDA
// min-blocks/CU: 2 blocks -> 4 waves/SIMD -> 512/4 = 128). This kernel needs
// ~210 VGPRs (acc[8][4] f4v = 128 alone); at 128 it spilled -> 1.55 GB FETCH /
// 514 MB WRITE of scratch traffic, MfmaUtil 9.8%. Arg=1 -> cap >= 256 -> no spill.
__global__ __launch_bounds__(512, 1) void k_lstm1_mfma(
    const float* __restrict__ c1, const float* __restrict__ c2,
    const short* __restrict__ WihP,  // packed, K=64  (2 k-chunks)
    const short* __restrict__ WhhP,  // packed, K=256 (8 k-chunks)
    const float* __restrict__ bih, const float* __restrict__ bhh,
    float* __restrict__ h1o, float* __restrict__ h2o)
{
  __shared__ __align__(16) short xs[64 * 72];    // 9.2 KB, pitch 72
  __shared__ __align__(16) short hs[64 * 264];   // 33.8 KB, pitch 264
  int bid = blockIdx.x;
  const float* src; float* dst;
  if (bid < 512) { src = c1; dst = h1o; } else { src = c2; dst = h2o; bid -= 512; }
  const size_t rowbase = (size_t)bid * 64;
  const int t = threadIdx.x;
  const int w = t >> 6;         // wave 0..7
  const int l15 = t & 15;
  const int kg = (t >> 4) & 3;  // k-group within wave

  const f4v fzero = {0.f, 0.f, 0.f, 0.f};

  // biases for this thread's 8 (gate, ug) slots
  float bsum[4][2];
#pragma unroll
  for (int g = 0; g < 4; ++g)
#pragma unroll
    for (int ug = 0; ug < 2; ++ug) {
      int u = w * 16 + ug * 128 + l15;
      bsum[g][ug] = bih[g * 256 + u] + bhh[g * 256 + u];
    }

  float creg[4][2][4];   // [row-tile][ug][reg]
#pragma unroll
  for (int rt = 0; rt < 4; ++rt)
#pragma unroll
    for (int ug = 0; ug < 2; ++ug)
#pragma unroll
      for (int r = 0; r < 4; ++r) creg[rt][ug][r] = 0.f;

  // stage x for step 0: thread t covers row t>>3, 8 contiguous elems
  {
    int row = t >> 3, d0 = (t & 7) * 8;
    alignas(16) short o[8];
#pragma unroll
    for (int j = 0; j < 8; ++j)
      o[j] = f2bf(src[(rowbase + row) * 512 + d0 + j]);
    *(s8v*)&xs[row * 72 + d0] = *(s8v*)o;
  }

  for (int step = 0; step < 8; ++step) {
    __syncthreads();   // xs (and hs) staged

    f4v acc[8][4];     // [q][row-tile]
#pragma unroll
    for (int q = 0; q < 8; ++q)
#pragma unroll
      for (int rt = 0; rt < 4; ++rt) acc[q][rt] = fzero;

    // ---- x-part: K = 64 (2 k-chunks)
#pragma unroll
    for (int kc = 0; kc < 2; ++kc) {
      s8v a[4];
#pragma unroll
      for (int rt = 0; rt < 4; ++rt)
        a[rt] = *(const s8v*)&xs[(rt * 16 + l15) * 72 + kc * 32 + kg * 8];
#pragma unroll
      for (int q = 0; q < 8; ++q) {
        int ct = w + 8 * q;
        s8v b = *(const s8v*)&WihP[((kc * 1024 + ct * 16 + l15) * 4 + kg) * 8];
#pragma unroll
        for (int rt = 0; rt < 4; ++rt)
          acc[q][rt] = __builtin_amdgcn_mfma_f32_16x16x32_bf16(a[rt], b, acc[q][rt], 0, 0, 0);
      }
    }
    // ---- h-part: K = 256 (8 k-chunks); h == 0 at step 0
    if (step > 0) {
      for (int kc = 0; kc < 8; ++kc) {
        s8v a[4];
#pragma unroll
        for (int rt = 0; rt < 4; ++rt)
          a[rt] = *(const s8v*)&hs[(rt * 16 + l15) * 264 + kc * 32 + kg * 8];
#pragma unroll
        for (int q = 0; q < 8; ++q) {
          int ct = w + 8 * q;
          s8v b = *(const s8v*)&WhhP[((kc * 1024 + ct * 16 + l15) * 4 + kg) * 8];
#pragma unroll
          for (int rt = 0; rt < 4; ++rt)
            acc[q][rt] = __builtin_amdgcn_mfma_f32_16x16x32_bf16(a[rt], b, acc[q][rt], 0, 0, 0);
        }
      }
    }

    __syncthreads();   // all LDS reads of this step done

    // ---- cell phase (register-local) + state write
#pragma unroll
    for (int rt = 0; rt < 4; ++rt)
#pragma unroll
      for (int ug = 0; ug < 2; ++ug)
#pragma unroll
        for (int r = 0; r < 4; ++r) {
          float iv = acc[0 + ug][rt][r] + bsum[0][ug];
          float fv = acc[2 + ug][rt][r] + bsum[1][ug];
          float gv = acc[4 + ug][rt][r] + bsum[2][ug];
          float ov = acc[6 + ug][rt][r] + bsum[3][ug];
          float is = 1.f / (1.f + __expf(-iv));
          float fs = 1.f / (1.f + __expf(-fv));
          float os = 1.f / (1.f + __expf(-ov));
          float gt = 1.f - 2.f / (__expf(2.f * gv) + 1.f);
          float cn = fs * creg[rt][ug][r] + is * gt;
          creg[rt][ug][r] = cn;
          float hv = os * (1.f - 2.f / (__expf(2.f * cn) + 1.f));
          int row = rt * 16 + kg * 4 + r;
          int u = w * 16 + ug * 128 + l15;
          if (step < 7) hs[row * 264 + u] = f2bf(hv);
          else          dst[(rowbase + row) * 256 + u] = hv;
        }

    if (step < 7) {   // stage next x (xs readers are past the barrier)
      int row = t >> 3, d0 = (t & 7) * 8;
      alignas(16) short o[8];
#pragma unroll
      for (int j = 0; j < 8; ++j)
        o[j] = f2bf(src[(rowbase + row) * 512 + (step + 1) * 64 + d0 + j]);
      *(s8v*)&xs[row * 72 + d0] = *(s8v*)o;
    }
  }
}

// ---------- lo = 0.5*(relu(h1@Wc^T+b) + relu(h2@Wc^T+b)) ----------
__global__ __launch_bounds__(512) void k_lo(
    const float* __restrict__ h1, const float* __restrict__ h2,
    const float* __restrict__ WT,  // [256][256]
    const float* __restrict__ cb, float* __restrict__ uo)
{
  __shared__ float as_[64 * 256];
  __shared__ float bs_[64 * 256];
  const size_t rowbase = (size_t)blockIdx.x * 64;
  const int t = threadIdx.x;
  const int u = t & 255;
  const int r0 = (t >> 8) * 32;
  for (int i = t; i < 64 * 256; i += 512) {
    as_[i] = h1[rowbase * 256 + i];
    bs_[i] = h2[rowbase * 256 + i];
  }
  __syncthreads();
  float a1[32], a2[32];
#pragma unroll
  for (int r = 0; r < 32; ++r) { a1[r] = 0.f; a2[r] = 0.f; }
  for (int k4 = 0; k4 < 64; ++k4) {
    float w0 = WT[(k4 * 4 + 0) * 256 + u];
    float w1 = WT[(k4 * 4 + 1) * 256 + u];
    float w2 = WT[(k4 * 4 + 2) * 256 + u];
    float w3 = WT[(k4 * 4 + 3) * 256 + u];
#pragma unroll
    for (int r = 0; r < 32; ++r) {
      float4 x1 = *(const float4*)&as_[(r0 + r) * 256 + k4 * 4];
      float4 x2 = *(const float4*)&bs_[(r0 + r) * 256 + k4 * 4];
      a1[r] = fmaf(x1.x, w0, fmaf(x1.y, w1, fmaf(x1.z, w2, fmaf(x1.w, w3, a1[r]))));
      a2[r] = fmaf(x2.x, w0, fmaf(x2.y, w1, fmaf(x2.z, w2, fmaf(x2.w, w3, a2[r]))));
    }
  }
  float bb = cb[u];
#pragma unroll
  for (int r = 0; r < 32; ++r) {
    float v = 0.5f * (fmaxf(a1[r] + bb, 0.f) + fmaxf(a2[r] + bb, 0.f));
    uo[(rowbase + r0 + r) * 256 + u] = v;
  }
}

// ---------- per-feature sum/sumsq over M rows of [M][256] ----------
__global__ __launch_bounds__(256) void k_colstats(const float* __restrict__ x, int M,
    float* __restrict__ s1, float* __restrict__ s2)
{
  __shared__ float rs[256], rss[256];
  int f = blockIdx.x, t = threadIdx.x;
  float s = 0.f, ss = 0.f;
  for (int r = t; r < M; r += 256) { float v = x[(size_t)r * 256 + f]; s += v; ss = fmaf(v, v, ss); }
  rs[t] = s; rss[t] = ss; __syncthreads();
  for (int o = 128; o > 0; o >>= 1) {
    if (t < o) { rs[t] += rs[t + o]; rss[t] += rss[t + o]; }
    __syncthreads();
  }
  if (!t) { s1[f] = rs[0]; s2[f] = rss[0]; }
}

// ---------- batchnorm apply (biased var), feature = idx&255 ----------
__global__ void k_bnapply(const float* __restrict__ in, float* __restrict__ out,
    const float* __restrict__ s1, const float* __restrict__ s2,
    const float* __restrict__ g, const float* __restrict__ b, float invM, int total)
{
  int idx = blockIdx.x * 256 + threadIdx.x;
  if (idx >= total) return;
  int f = idx & 255;
  float m = s1[f] * invM;
  float var = s2[f] * invM - m * m;
  out[idx] = (in[idx] - m) * rsqrtf(var + 1e-5f) * g[f] + b[f];
}

// ---------- sample encoder: so = relu(samples@Ws^T+b)*mask ----------
__global__ __launch_bounds__(256) void k_samp(
    const float* __restrict__ smp, const float* __restrict__ WT,  // [1000][256]
    const float* __restrict__ sb, const float* __restrict__ mask, float* __restrict__ so)
{
  __shared__ float xs[16 * 1000];   // 62.5 KB
  const size_t rowbase = (size_t)blockIdx.x * 16;
  const int t = threadIdx.x; const int u = t;
  for (int i = t; i < 16000; i += 256) xs[i] = smp[rowbase * 1000 + i];
  __syncthreads();
  float acc[16];
#pragma unroll
  for (int r = 0; r < 16; ++r) acc[r] = 0.f;
  for (int k4 = 0; k4 < 250; ++k4) {
    float w0 = WT[(k4 * 4 + 0) * 256 + u];
    float w1 = WT[(k4 * 4 + 1) * 256 + u];
    float w2 = WT[(k4 * 4 + 2) * 256 + u];
    float w3 = WT[(k4 * 4 + 3) * 256 + u];
#pragma unroll
    for (int r = 0; r < 16; ++r) {
      float4 xv = *(const float4*)&xs[r * 1000 + k4 * 4];
      acc[r] = fmaf(xv.x, w0, fmaf(xv.y, w1, fmaf(xv.z, w2, fmaf(xv.w, w3, acc[r]))));
    }
  }
#pragma unroll
  for (int r = 0; r < 16; ++r)
    so[(rowbase + r) * 256 + u] = fmaxf(acc[r] + sb[u], 0.f) * mask[rowbase + r];
}

// ---------- gx = feats @ W_ih2^T + b_ih2 + b_hh2 (x-part of lstm2, all levels) ----------
// feats = [ops(15) | lo(256) | so(256)], output gate-interleaved [row][256][4]
// 32 rows/block, 16 rows/thread (spill-safe under the 128-VGPR cap).
__global__ __launch_bounds__(512, 2) void k_gx(
    const float* __restrict__ ops, const float* __restrict__ lo, const float* __restrict__ so,
    const float* __restrict__ WT,  // [527][256][4]
    const float* __restrict__ bih, const float* __restrict__ bhh, float* __restrict__ gx)
{
  __shared__ float opss[32 * 15];
  __shared__ float los[32 * 256];
  __shared__ float sos[32 * 256];
  const size_t rowbase = (size_t)blockIdx.x * 32;
  const int t = threadIdx.x;
  const int u = t & 255;
  const int r0 = (t >> 8) * 16;
  for (int i = t; i < 32 * 15; i += 512) opss[i] = ops[rowbase * 15 + i];
  for (int i = t; i < 32 * 256; i += 512) { los[i] = lo[rowbase * 256 + i]; sos[i] = so[rowbase * 256 + i]; }
  __syncthreads();
  float4 bsum;
  bsum.x = bih[u]       + bhh[u];
  bsum.y = bih[256 + u] + bhh[256 + u];
  bsum.z = bih[512 + u] + bhh[512 + u];
  bsum.w = bih[768 + u] + bhh[768 + u];
  float4 acc[16];
#pragma unroll
  for (int r = 0; r < 16; ++r) acc[r] = bsum;
  for (int k = 0; k < 15; ++k) {
    float4 w = *(const float4*)&WT[((size_t)k * 256 + u) * 4];
#pragma unroll
    for (int r = 0; r < 16; ++r) {
      float x = opss[(r0 + r) * 15 + k];
      acc[r].x = fmaf(x, w.x, acc[r].x);
      acc[r].y = fmaf(x, w.y, acc[r].y);
      acc[r].z = fmaf(x, w.z, acc[r].z);
      acc[r].w = fmaf(x, w.w, acc[r].w);
    }
  }
  for (int k4 = 0; k4 < 64; ++k4) {
    float4 w0 = *(const float4*)&WT[((15 + k4 * 4 + 0) * 256 + u) * 4];
    float4 w1 = *(const float4*)&WT[((15 + k4 * 4 + 1) * 256 + u) * 4];
    float4 w2 = *(const float4*)&WT[((15 + k4 * 4 + 2) * 256 + u) * 4];
    float4 w3 = *(const float4*)&WT[((15 + k4 * 4 + 3) * 256 + u) * 4];
#pragma unroll
    for (int r = 0; r < 16; ++r) {
      float4 xv = *(const float4*)&los[(r0 + r) * 256 + k4 * 4];
      fma_gates(acc[r], xv, w0, w1, w2, w3);
    }
  }
  for (int k4 = 0; k4 < 64; ++k4) {
    float4 w0 = *(const float4*)&WT[((271 + k4 * 4 + 0) * 256 + u) * 4];
    float4 w1 = *(const float4*)&WT[((271 + k4 * 4 + 1) * 256 + u) * 4];
    float4 w2 = *(const float4*)&WT[((271 + k4 * 4 + 2) * 256 + u) * 4];
    float4 w3 = *(const float4*)&WT[((271 + k4 * 4 + 3) * 256 + u) * 4];
#pragma unroll
    for (int r = 0; r < 16; ++r) {
      float4 xv = *(const float4*)&sos[(r0 + r) * 256 + k4 * 4];
      fma_gates(acc[r], xv, w0, w1, w2, w3);
    }
  }
#pragma unroll
  for (int r = 0; r < 16; ++r)
    *(float4*)&gx[(rowbase + r0 + r) * 1024 + u * 4] = acc[r];
}

// ---------- level L-1: h2=c2=0, cell directly from gx ----------
__global__ void k_level_first(const float* __restrict__ gxl,
                              float* __restrict__ h, float* __restrict__ c) {
  size_t idx = (size_t)blockIdx.x * 256 + threadIdx.x;  // < N*256
  float4 g = *(const float4*)&gxl[idx * 4];
  float cn = sigf(g.x) * tanhf(g.z);
  h[idx] = sigf(g.w) * tanhf(cn);
  c[idx] = cn;
}

// ---------- one tree level: gather children, recurrent GEMM (K=256), cell ----------
__global__ __launch_bounds__(256) void k_level(
    const float* __restrict__ gxl, const int* __restrict__ map,
    const float* __restrict__ hprev, const float* __restrict__ cprev,
    const float* __restrict__ WT,   // [256][256][4]
    float* __restrict__ hnext, float* __restrict__ cnext)
{
  __shared__ float h2s[8 * 256];
  __shared__ int ms[16];
  const int rowbase = blockIdx.x * 8;
  const int t = threadIdx.x;
  const int u = t;
  if (t < 16) ms[t] = map[rowbase * 2 + t];
  __syncthreads();
  for (int i = t; i < 8 * 256; i += 256) {
    int r = i >> 8, k = i & 255;
    int a = ms[r * 2], b = ms[r * 2 + 1];
    float v = (a ? hprev[(size_t)(a - 1) * 256 + k] : 0.f)
            + (b ? hprev[(size_t)(b - 1) * 256 + k] : 0.f);
    h2s[i] = 0.5f * v;
  }
  __syncthreads();
  float4 acc[8];
  float c2[8];
#pragma unroll
  for (int r = 0; r < 8; ++r) {
    int a = ms[r * 2], b = ms[r * 2 + 1];
    c2[r] = 0.5f * ((a ? cprev[(size_t)(a - 1) * 256 + u] : 0.f)
                  + (b ? cprev[(size_t)(b - 1) * 256 + u] : 0.f));
    acc[r] = *(const float4*)&gxl[(size_t)(rowbase + r) * 1024 + u * 4];
  }
  for (int k4 = 0; k4 < 64; ++k4) {
    float4 w0 = *(const float4*)&WT[((k4 * 4 + 0) * 256 + u) * 4];
    float4 w1 = *(const float4*)&WT[((k4 * 4 + 1) * 256 + u) * 4];
    float4 w2 = *(const float4*)&WT[((k4 * 4 + 2) * 256 + u) * 4];
    float4 w3 = *(const float4*)&WT[((k4 * 4 + 3) * 256 + u) * 4];
#pragma unroll
    for (int r = 0; r < 8; ++r) {
      float4 xv = *(const float4*)&h2s[r * 256 + k4 * 4];
      fma_gates(acc[r], xv, w0, w1, w2, w3);
    }
  }
#pragma unroll
  for (int r = 0; r < 8; ++r) {
    float cn = sigf(acc[r].y) * c2[r] + sigf(acc[r].x) * tanhf(acc[r].z);
    hnext[(size_t)(rowbase + r) * 256 + u] = sigf(acc[r].w) * tanhf(cn);
    cnext[(size_t)(rowbase + r) * 256 + u] = cn;
  }
}

// ---------- head GEMM (optional BN on input, ReLU out) ----------
__global__ __launch_bounds__(256) void k_head(
    const float* __restrict__ A, const float* __restrict__ WT, const float* __restrict__ bias,
    float* __restrict__ out,
    const float* __restrict__ s1, const float* __restrict__ s2,
    const float* __restrict__ bg, const float* __restrict__ bb, float invM)
{
  __shared__ float as[16 * 256];
  const size_t rowbase = (size_t)blockIdx.x * 16;
  const int t = threadIdx.x; const int u = t;
  for (int i = t; i < 16 * 256; i += 256) {
    float v = A[rowbase * 256 + i];
    if (s1) {
      int f = i & 255;
      float m = s1[f] * invM;
      float var = s2[f] * invM - m * m;
      v = (v - m) * rsqrtf(var + 1e-5f) * bg[f] + bb[f];
    }
    as[i] = v;
  }
  __syncthreads();
  float acc[16];
#pragma unroll
  for (int r = 0; r < 16; ++r) acc[r] = 0.f;
  for (int k4 = 0; k4 < 64; ++k4) {
    float w0 = WT[(k4 * 4 + 0) * 256 + u];
    float w1 = WT[(k4 * 4 + 1) * 256 + u];
    float w2 = WT[(k4 * 4 + 2) * 256 + u];
    float w3 = WT[(k4 * 4 + 3) * 256 + u];
#pragma unroll
    for (int r = 0; r < 16; ++r) {
      float4 xv = *(const float4*)&as[r * 256 + k4 * 4];
      acc[r] = fmaf(xv.x, w0, fmaf(xv.y, w1, fmaf(xv.z, w2, fmaf(xv.w, w3, acc[r]))));
    }
  }
#pragma unroll
  for (int r = 0; r < 16; ++r)
    out[(rowbase + r) * 256 + u] = fmaxf(acc[r] + bias[u], 0.f);
}

// ---------- final sigmoid dot-product, written to 3 output slots ----------
__global__ void k_head_out(const float* __restrict__ Y, const float* __restrict__ Wo,
                           const float* __restrict__ bo,
                           float* __restrict__ d0, float* __restrict__ d1, float* __restrict__ d2)
{
  int row = blockIdx.x * 256 + threadIdx.x;
  if (row >= N_) return;
  float s = 0.f;
  for (int k = 0; k < 256; ++k) s = fmaf(Y[(size_t)row * 256 + k], Wo[k], s);
  float o = sigf(s + bo[0]);
  d0[row] = o; d1[row] = o; d2[row] = o;
}

extern "C" void kernel_launch(void* const* d_in, const int* in_sizes, int n_in,
                              void* d_out, int out_size, void* d_ws, size_t ws_size,
                              hipStream_t stream)
{
  (void)in_sizes; (void)n_in; (void)out_size; (void)ws_size;
  const float* ops     = (const float*)d_in[0];
  const float* cond1   = (const float*)d_in[2];
  const float* cond2   = (const float*)d_in[3];
  const float* smp     = (const float*)d_in[4];
  const float* mask    = (const float*)d_in[5];
  const int*   mapping = (const int*)d_in[6];
  const float* W_ih1 = (const float*)d_in[7];
  const float* W_hh1 = (const float*)d_in[8];
  const float* b_ih1 = (const float*)d_in[9];
  const float* b_hh1 = (const float*)d_in[10];
  const float* W_ih2 = (const float*)d_in[11];
  const float* W_hh2 = (const float*)d_in[12];
  const float* b_ih2 = (const float*)d_in[13];
  const float* b_hh2 = (const float*)d_in[14];
  const float* cond_W = (const float*)d_in[15];
  const float* cond_b = (const float*)d_in[16];
  const float* samp_W = (const float*)d_in[17];
  const float* samp_b = (const float*)d_in[18];
  const float* bn1_g = (const float*)d_in[19];
  const float* bn1_b = (const float*)d_in[20];
  const float* bn2_g = (const float*)d_in[21];
  const float* bn2_b = (const float*)d_in[22];
  const float* bn3_g = (const float*)d_in[23];
  const float* bn3_b = (const float*)d_in[24];
  const float* hW2[2] = {(const float*)d_in[25], (const float*)d_in[31]};
  const float* hb2[2] = {(const float*)d_in[26], (const float*)d_in[32]};
  const float* hW3[2] = {(const float*)d_in[27], (const float*)d_in[33]};
  const float* hb3[2] = {(const float*)d_in[28], (const float*)d_in[34]};
  const float* hWo[2] = {(const float*)d_in[29], (const float*)d_in[35]};
  const float* hbo[2] = {(const float*)d_in[30], (const float*)d_in[36]};
  float* out = (float*)d_out;
  float* ws = (float*)d_ws;

  // workspace layout (floats, 256B-aligned blocks). Total ~224 MB.
  size_t p = 0;
  auto alloc = [&](size_t n) { size_t r = p; p += (n + 63) & ~(size_t)63; return r; };
  float* WihPf  = ws + alloc(64 * 1024 / 2);        // packed bf16, 65536 shorts
  float* WhhPf  = ws + alloc(256 * 1024 / 2);       // packed bf16, 262144 shorts
  float* Wih2T  = ws + alloc((size_t)527 * 1024);
  float* Whh2T  = ws + alloc(256 * 1024);
  float* condWT = ws + alloc(256 * 256);
  float* sampWT = ws + alloc(1000 * 256);
  float* w2T0 = ws + alloc(256 * 256);
  float* w3T0 = ws + alloc(256 * 256);
  float* w2T1 = ws + alloc(256 * 256);
  float* w3T1 = ws + alloc(256 * 256);
  float* s1a = ws + alloc(256); float* s2a = ws + alloc(256);
  float* s1b = ws + alloc(256); float* s2b = ws + alloc(256);
  float* s1c = ws + alloc(256); float* s2c = ws + alloc(256);
  float* z  = ws + alloc((size_t)N_ * 256);
  float* yA = ws + alloc((size_t)N_ * 256);
  float* yB = ws + alloc((size_t)N_ * 256);
  float* hA = ws + alloc((size_t)N_ * 256);
  float* cA = ws + alloc((size_t)N_ * 256);
  float* hB = ws + alloc((size_t)N_ * 256);
  float* cB = ws + alloc((size_t)N_ * 256);
  float* lo = ws + alloc((size_t)LN_ * 256);
  float* so = ws + alloc((size_t)LN_ * 256);
  float* gx = ws + alloc((size_t)LN_ * 1024);
  float* h1 = gx;                       // h1/h2 live only until k_lo; gx reuses region
  float* h2 = gx + (size_t)LN_ * 256;
  short* WihP = (short*)WihPf;
  short* WhhP = (short*)WhhPf;

  const float* w2T[2] = {w2T0, w2T1};
  const float* w3T[2] = {w3T0, w3T1};

  // --- weight transforms (one-shot, tiny) ---
  k_pack_gates<<<(1024 * 64) / 256, 256, 0, stream>>>(W_ih1, WihP, 64);
  k_pack_gates<<<(1024 * 256) / 256, 256, 0, stream>>>(W_hh1, WhhP, 256);
  k_tr_gates<<<(527 * 1024 + 255) / 256, 256, 0, stream>>>(W_ih2, Wih2T, 527);
  k_tr_gates<<<(256 * 1024) / 256, 256, 0, stream>>>(W_hh2, Whh2T, 256);
  k_tr_plain<<<256, 256, 0, stream>>>(cond_W, condWT, 256);
  k_tr_plain<<<1000, 256, 0, stream>>>(samp_W, sampWT, 1000);
  k_tr_plain<<<256, 256, 0, stream>>>(hW2[0], w2T0, 256);
  k_tr_plain<<<256, 256, 0, stream>>>(hW3[0], w3T0, 256);
  k_tr_plain<<<256, 256, 0, stream>>>(hW2[1], w2T1, 256);
  k_tr_plain<<<256, 256, 0, stream>>>(hW3[1], w3T1, 256);

  // --- stage A: shared lstm1 via MFMA over both condition tensors ---
  k_lstm1_mfma<<<1024, 512, 0, stream>>>(cond1, cond2, WihP, WhhP, b_ih1, b_hh1, h1, h2);

  // --- stage B: lo = bn1( 0.5*(relu(h1@Wc+b)+relu(h2@Wc+b)) ) ---
  k_lo<<<512, 512, 0, stream>>>(h1, h2, condWT, cond_b, lo);
  k_colstats<<<256, 256, 0, stream>>>(lo, LN_, s1a, s2a);
  k_bnapply<<<(LN_ * 256) / 256, 256, 0, stream>>>(lo, lo, s1a, s2a, bn1_g, bn1_b, 1.f / LN_, LN_ * 256);

  // --- stage C: sample encoder ---
  k_samp<<<LN_ / 16, 256, 0, stream>>>(smp, sampWT, samp_b, mask, so);

  // --- stage D: level-parallel x-part of lstm2 (biases folded in) ---
  k_gx<<<LN_ / 32, 512, 0, stream>>>(ops, lo, so, Wih2T, b_ih2, b_hh2, gx);

  // --- stage E: sequential tree recurrence ---
  k_level_first<<<(N_ * 256) / 256, 256, 0, stream>>>(gx + (size_t)15 * N_ * 1024, hA, cA);
  float* hc = hA; float* cc = cA; float* hn = hB; float* cn = cB;
  for (int l = 14; l >= 0; --l) {
    k_level<<<N_ / 8, 256, 0, stream>>>(gx + (size_t)l * N_ * 1024,
                                        mapping + (size_t)l * N_ * 2,
                                        hc, cc, Whh2T, hn, cn);
    float* tp;
    tp = hc; hc = hn; hn = tp;
    tp = cc; cc = cn; cn = tp;
  }

  // --- stage F: heads ---
  k_colstats<<<256, 256, 0, stream>>>(hc, N_, s1b, s2b);
  k_bnapply<<<(N_ * 256) / 256, 256, 0, stream>>>(hc, z, s1b, s2b, bn2_g, bn2_b, 1.f / N_, N_ * 256);
  for (int hd = 0; hd < 2; ++hd) {
    k_head<<<N_ / 16, 256, 0, stream>>>(z, w2T[hd], hb2[hd], yA,
                                        nullptr, nullptr, nullptr, nullptr, 0.f);
    k_colstats<<<256, 256, 0, stream>>>(yA, N_, s1c, s2c);
    k_head<<<N_ / 16, 256, 0, stream>>>(yA, w3T[hd], hb3[hd], yB,
                                        s1c, s2c, bn3_g, bn3_b, 1.f / N_);
    // output layout: o1 | o2 | task1(=o1,o1) | task2(=o2,o2)
    float* o0  = out + (hd == 0 ? 0 : N_);
    float* o1p = out + (hd == 0 ? 2 * N_ : 4 * N_);
    float* o2p = out + (hd == 0 ? 3 * N_ : 5 * N_);
    k_head_out<<<N_ / 256, 256, 0, stream>>>(yB, hWo[hd], hbo[hd], o0, o1p, o2p);
  }
}

// Round 8
// 3423.830 us; speedup vs baseline: 1.0297x; 1.0297x over previous
//
#include <hip/hip_runtime.h>
#include <hip/hip_bf16.h>
#include <math.h>

// Problem dims
#define L_   16
#define N_   2048
#define C_   8
#define D_   64
#define H_   256
#define HID_ 256
#define F_   527
#define LN_  (L_*N_)   // 32768

typedef __attribute__((ext_vector_type(8))) short s8v;   // 8 bf16 = 4 VGPR
typedef __attribute__((ext_vector_type(4))) short s4v;   // 4 bf16 = 2 VGPR
typedef __attribute__((ext_vector_type(4))) float f4v;   // MFMA 16x16 accumulator

__device__ __forceinline__ float sigf(float x) { return 1.f / (1.f + expf(-x)); }

// float -> bf16 bits, round-to-nearest-even
__device__ __forceinline__ short f2bf(float f) {
  unsigned u = __float_as_uint(f);
  unsigned r = (u + 0x7fffu + ((u >> 16) & 1u)) >> 16;
  return (short)(r & 0xffffu);
}

__device__ __forceinline__ void fma_gates(float4& a, float4 xv,
                                          float4 w0, float4 w1, float4 w2, float4 w3) {
  a.x = fmaf(xv.x, w0.x, fmaf(xv.y, w1.x, fmaf(xv.z, w2.x, fmaf(xv.w, w3.x, a.x))));
  a.y = fmaf(xv.x, w0.y, fmaf(xv.y, w1.y, fmaf(xv.z, w2.y, fmaf(xv.w, w3.y, a.y))));
  a.z = fmaf(xv.x, w0.z, fmaf(xv.y, w1.z, fmaf(xv.z, w2.z, fmaf(xv.w, w3.z, a.z))));
  a.w = fmaf(xv.x, w0.w, fmaf(xv.y, w1.w, fmaf(xv.z, w2.w, fmaf(xv.w, w3.w, a.w))));
}

// ---------- weight pre-transposes ----------
// W [1024][K] -> out [K][256][4]  (gate-interleaved: out[k][u][j] = W[j*256+u][k])
__global__ void k_tr_gates(const float* __restrict__ W, float* __restrict__ out, int K) {
  int idx = blockIdx.x * 256 + threadIdx.x;
  if (idx >= K * 1024) return;
  int k = idx >> 10, r = idx & 1023;
  int u = r >> 2, j = r & 3;
  out[idx] = W[(size_t)(j * 256 + u) * K + k];
}

// W [256][Cn] -> out [Cn][256]
__global__ void k_tr_plain(const float* __restrict__ W, float* __restrict__ out, int Cn) {
  int idx = blockIdx.x * 256 + threadIdx.x;
  if (idx >= 256 * Cn) return;
  int c = idx >> 8, r = idx & 255;
  out[idx] = W[(size_t)r * Cn + c];
}

// W [1024][K] fp32 -> bf16 MFMA-fragment-packed:
// out[((kc*1024 + n)*4 + kg)*8 + j] = bf16(W[n][kc*32 + kg*8 + j])
__global__ void k_pack_gates(const float* __restrict__ W, short* __restrict__ out, int K) {
  int idx = blockIdx.x * 256 + threadIdx.x;
  if (idx >= 1024 * K) return;
  int j  = idx & 7;
  int kg = (idx >> 3) & 3;
  int n  = (idx >> 5) & 1023;
  int kc = idx >> 15;
  int k  = kc * 32 + kg * 8 + j;
  out[idx] = f2bf(W[(size_t)n * K + k]);
}

// ---------- lstm1 via MFMA (bf16 in, fp32 acc) ----------
// 8-step LSTM over [32768, 8, 64] x2 inputs, shared weights.
// grid 1024 x 1024 threads (16 waves): blocks [0,512)->cond1, [512,1024)->cond2.
// 64 rows/block. Wave wv=(ug<<3)|w7 owns gates 0..3 of unit-group ug:
// col-tile ct = w7 + 16*gate + 8*ug  (union over w7,ug,gate = all 64 tiles).
// Per thread: acc[4][4] f4v = 64 VGPR (+creg 16 +a 16 +bsum 4 +b 4 +addr ~15
// ~= 120) -> FITS the 128-VGPR cap this toolchain enforces for large blocks
// (rounds 6/7: launch_bounds 2nd arg {2,1} both gave cap=128 -> acc[8][4]
// spilled: 1.55 GB FETCH / 514 MB WRITE scratch traffic, MfmaUtil 9.8%).
// Arithmetic identical to the verified round-6 kernel (absmax 0.0039) --
// only the wave->tile mapping changed (q=2*gate+ug was in-wave, now ug is
// the wave's high bit). A/B frags share lane->(idx,kg,j) decomposition ->
// k-permutation cancels; C/D layout per m89/m91: col=lane&15, row=(lane>>4)*4+reg.
__global__ __launch_bounds__(1024, 1) void k_lstm1_mfma(
    const float* __restrict__ c1, const float* __restrict__ c2,
    const short* __restrict__ WihP,  // packed, K=64  (2 k-chunks)
    const short* __restrict__ WhhP,  // packed, K=256 (8 k-chunks)
    const float* __restrict__ bih, const float* __restrict__ bhh,
    float* __restrict__ h1o, float* __restrict__ h2o)
{
  __shared__ __align__(16) short xs[64 * 72];    // 9.2 KB, pitch 72
  __shared__ __align__(16) short hs[64 * 264];   // 33.8 KB, pitch 264
  int bid = blockIdx.x;
  const float* src; float* dst;
  if (bid < 512) { src = c1; dst = h1o; } else { src = c2; dst = h2o; bid -= 512; }
  const size_t rowbase = (size_t)bid * 64;
  const int t = threadIdx.x;
  const int wv = t >> 6;         // wave 0..15
  const int w7 = wv & 7;
  const int ug = wv >> 3;        // unit-group (high half of 256 units)
  const int l15 = t & 15;
  const int kg = (t >> 4) & 3;   // k-group within wave
  const int u = w7 * 16 + ug * 128 + l15;   // this thread's output unit

  const f4v fzero = {0.f, 0.f, 0.f, 0.f};

  float bsum[4];
#pragma unroll
  for (int g = 0; g < 4; ++g) bsum[g] = bih[g * 256 + u] + bhh[g * 256 + u];

  float creg[4][4];   // [row-tile][reg]
#pragma unroll
  for (int rt = 0; rt < 4; ++rt)
#pragma unroll
    for (int r = 0; r < 4; ++r) creg[rt][r] = 0.f;

  // stage x for step 0: thread t covers row t>>4, 4 contiguous elems
  {
    int row = t >> 4, d0 = (t & 15) * 4;
    alignas(8) short o[4];
#pragma unroll
    for (int j = 0; j < 4; ++j)
      o[j] = f2bf(src[(rowbase + row) * 512 + d0 + j]);
    *(s4v*)&xs[row * 72 + d0] = *(s4v*)o;
  }

  for (int step = 0; step < 8; ++step) {
    __syncthreads();   // xs (and hs) staged

    f4v acc[4][4];     // [gate][row-tile]
#pragma unroll
    for (int g = 0; g < 4; ++g)
#pragma unroll
      for (int rt = 0; rt < 4; ++rt) acc[g][rt] = fzero;

    // ---- x-part: K = 64 (2 k-chunks)
#pragma unroll
    for (int kc = 0; kc < 2; ++kc) {
      s8v a[4];
#pragma unroll
      for (int rt = 0; rt < 4; ++rt)
        a[rt] = *(const s8v*)&xs[(rt * 16 + l15) * 72 + kc * 32 + kg * 8];
#pragma unroll
      for (int g = 0; g < 4; ++g) {
        int ct = w7 + 16 * g + 8 * ug;
        s8v b = *(const s8v*)&WihP[((kc * 1024 + ct * 16 + l15) * 4 + kg) * 8];
#pragma unroll
        for (int rt = 0; rt < 4; ++rt)
          acc[g][rt] = __builtin_amdgcn_mfma_f32_16x16x32_bf16(a[rt], b, acc[g][rt], 0, 0, 0);
      }
    }
    // ---- h-part: K = 256 (8 k-chunks); h == 0 at step 0
    if (step > 0) {
      for (int kc = 0; kc < 8; ++kc) {
        s8v a[4];
#pragma unroll
        for (int rt = 0; rt < 4; ++rt)
          a[rt] = *(const s8v*)&hs[(rt * 16 + l15) * 264 + kc * 32 + kg * 8];
#pragma unroll
        for (int g = 0; g < 4; ++g) {
          int ct = w7 + 16 * g + 8 * ug;
          s8v b = *(const s8v*)&WhhP[((kc * 1024 + ct * 16 + l15) * 4 + kg) * 8];
#pragma unroll
          for (int rt = 0; rt < 4; ++rt)
            acc[g][rt] = __builtin_amdgcn_mfma_f32_16x16x32_bf16(a[rt], b, acc[g][rt], 0, 0, 0);
        }
      }
    }

    __syncthreads();   // all LDS reads of this step done

    // ---- cell phase (register-local) + state write
#pragma unroll
    for (int rt = 0; rt < 4; ++rt)
#pragma unroll
      for (int r = 0; r < 4; ++r) {
        float iv = acc[0][rt][r] + bsum[0];
        float fv = acc[1][rt][r] + bsum[1];
        float gv = acc[2][rt][r] + bsum[2];
        float ov = acc[3][rt][r] + bsum[3];
        float is = 1.f / (1.f + __expf(-iv));
        float fs = 1.f / (1.f + __expf(-fv));
        float os = 1.f / (1.f + __expf(-ov));
        float gt = 1.f - 2.f / (__expf(2.f * gv) + 1.f);
        float cn = fs * creg[rt][r] + is * gt;
        creg[rt][r] = cn;
        float hv = os * (1.f - 2.f / (__expf(2.f * cn) + 1.f));
        int row = rt * 16 + kg * 4 + r;
        if (step < 7) hs[row * 264 + u] = f2bf(hv);
        else          dst[(rowbase + row) * 256 + u] = hv;
      }

    if (step < 7) {   // stage next x (xs readers are past the barrier)
      int row = t >> 4, d0 = (t & 15) * 4;
      alignas(8) short o[4];
#pragma unroll
      for (int j = 0; j < 4; ++j)
        o[j] = f2bf(src[(rowbase + row) * 512 + (step + 1) * 64 + d0 + j]);
      *(s4v*)&xs[row * 72 + d0] = *(s4v*)o;
    }
  }
}

// ---------- lo = 0.5*(relu(h1@Wc^T+b) + relu(h2@Wc^T+b)) ----------
__global__ __launch_bounds__(512) void k_lo(
    const float* __restrict__ h1, const float* __restrict__ h2,
    const float* __restrict__ WT,  // [256][256]
    const float* __restrict__ cb, float* __restrict__ uo)
{
  __shared__ float as_[64 * 256];
  __shared__ float bs_[64 * 256];
  const size_t rowbase = (size_t)blockIdx.x * 64;
  const int t = threadIdx.x;
  const int u = t & 255;
  const int r0 = (t >> 8) * 32;
  for (int i = t; i < 64 * 256; i += 512) {
    as_[i] = h1[rowbase * 256 + i];
    bs_[i] = h2[rowbase * 256 + i];
  }
  __syncthreads();
  float a1[32], a2[32];
#pragma unroll
  for (int r = 0; r < 32; ++r) { a1[r] = 0.f; a2[r] = 0.f; }
  for (int k4 = 0; k4 < 64; ++k4) {
    float w0 = WT[(k4 * 4 + 0) * 256 + u];
    float w1 = WT[(k4 * 4 + 1) * 256 + u];
    float w2 = WT[(k4 * 4 + 2) * 256 + u];
    float w3 = WT[(k4 * 4 + 3) * 256 + u];
#pragma unroll
    for (int r = 0; r < 32; ++r) {
      float4 x1 = *(const float4*)&as_[(r0 + r) * 256 + k4 * 4];
      float4 x2 = *(const float4*)&bs_[(r0 + r) * 256 + k4 * 4];
      a1[r] = fmaf(x1.x, w0, fmaf(x1.y, w1, fmaf(x1.z, w2, fmaf(x1.w, w3, a1[r]))));
      a2[r] = fmaf(x2.x, w0, fmaf(x2.y, w1, fmaf(x2.z, w2, fmaf(x2.w, w3, a2[r]))));
    }
  }
  float bb = cb[u];
#pragma unroll
  for (int r = 0; r < 32; ++r) {
    float v = 0.5f * (fmaxf(a1[r] + bb, 0.f) + fmaxf(a2[r] + bb, 0.f));
    uo[(rowbase + r0 + r) * 256 + u] = v;
  }
}

// ---------- per-feature sum/sumsq over M rows of [M][256] ----------
__global__ __launch_bounds__(256) void k_colstats(const float* __restrict__ x, int M,
    float* __restrict__ s1, float* __restrict__ s2)
{
  __shared__ float rs[256], rss[256];
  int f = blockIdx.x, t = threadIdx.x;
  float s = 0.f, ss = 0.f;
  for (int r = t; r < M; r += 256) { float v = x[(size_t)r * 256 + f]; s += v; ss = fmaf(v, v, ss); }
  rs[t] = s; rss[t] = ss; __syncthreads();
  for (int o = 128; o > 0; o >>= 1) {
    if (t < o) { rs[t] += rs[t + o]; rss[t] += rss[t + o]; }
    __syncthreads();
  }
  if (!t) { s1[f] = rs[0]; s2[f] = rss[0]; }
}

// ---------- batchnorm apply (biased var), feature = idx&255 ----------
__global__ void k_bnapply(const float* __restrict__ in, float* __restrict__ out,
    const float* __restrict__ s1, const float* __restrict__ s2,
    const float* __restrict__ g, const float* __restrict__ b, float invM, int total)
{
  int idx = blockIdx.x * 256 + threadIdx.x;
  if (idx >= total) return;
  int f = idx & 255;
  float m = s1[f] * invM;
  float var = s2[f] * invM - m * m;
  out[idx] = (in[idx] - m) * rsqrtf(var + 1e-5f) * g[f] + b[f];
}

// ---------- sample encoder: so = relu(samples@Ws^T+b)*mask ----------
__global__ __launch_bounds__(256) void k_samp(
    const float* __restrict__ smp, const float* __restrict__ WT,  // [1000][256]
    const float* __restrict__ sb, const float* __restrict__ mask, float* __restrict__ so)
{
  __shared__ float xs[16 * 1000];   // 62.5 KB
  const size_t rowbase = (size_t)blockIdx.x * 16;
  const int t = threadIdx.x; const int u = t;
  for (int i = t; i < 16000; i += 256) xs[i] = smp[rowbase * 1000 + i];
  __syncthreads();
  float acc[16];
#pragma unroll
  for (int r = 0; r < 16; ++r) acc[r] = 0.f;
  for (int k4 = 0; k4 < 250; ++k4) {
    float w0 = WT[(k4 * 4 + 0) * 256 + u];
    float w1 = WT[(k4 * 4 + 1) * 256 + u];
    float w2 = WT[(k4 * 4 + 2) * 256 + u];
    float w3 = WT[(k4 * 4 + 3) * 256 + u];
#pragma unroll
    for (int r = 0; r < 16; ++r) {
      float4 xv = *(const float4*)&xs[r * 1000 + k4 * 4];
      acc[r] = fmaf(xv.x, w0, fmaf(xv.y, w1, fmaf(xv.z, w2, fmaf(xv.w, w3, acc[r]))));
    }
  }
#pragma unroll
  for (int r = 0; r < 16; ++r)
    so[(rowbase + r) * 256 + u] = fmaxf(acc[r] + sb[u], 0.f) * mask[rowbase + r];
}

// ---------- gx = feats @ W_ih2^T + b_ih2 + b_hh2 (x-part of lstm2, all levels) ----------
// feats = [ops(15) | lo(256) | so(256)], output gate-interleaved [row][256][4]
// 32 rows/block, 16 rows/thread (spill-safe under the 128-VGPR cap).
__global__ __launch_bounds__(512, 2) void k_gx(
    const float* __restrict__ ops, const float* __restrict__ lo, const float* __restrict__ so,
    const float* __restrict__ WT,  // [527][256][4]
    const float* __restrict__ bih, const float* __restrict__ bhh, float* __restrict__ gx)
{
  __shared__ float opss[32 * 15];
  __shared__ float los[32 * 256];
  __shared__ float sos[32 * 256];
  const size_t rowbase = (size_t)blockIdx.x * 32;
  const int t = threadIdx.x;
  const int u = t & 255;
  const int r0 = (t >> 8) * 16;
  for (int i = t; i < 32 * 15; i += 512) opss[i] = ops[rowbase * 15 + i];
  for (int i = t; i < 32 * 256; i += 512) { los[i] = lo[rowbase * 256 + i]; sos[i] = so[rowbase * 256 + i]; }
  __syncthreads();
  float4 bsum;
  bsum.x = bih[u]       + bhh[u];
  bsum.y = bih[256 + u] + bhh[256 + u];
  bsum.z = bih[512 + u] + bhh[512 + u];
  bsum.w = bih[768 + u] + bhh[768 + u];
  float4 acc[16];
#pragma unroll
  for (int r = 0; r < 16; ++r) acc[r] = bsum;
  for (int k = 0; k < 15; ++k) {
    float4 w = *(const float4*)&WT[((size_t)k * 256 + u) * 4];
#pragma unroll
    for (int r = 0; r < 16; ++r) {
      float x = opss[(r0 + r) * 15 + k];
      acc[r].x = fmaf(x, w.x, acc[r].x);
      acc[r].y = fmaf(x, w.y, acc[r].y);
      acc[r].z = fmaf(x, w.z, acc[r].z);
      acc[r].w = fmaf(x, w.w, acc[r].w);
    }
  }
  for (int k4 = 0; k4 < 64; ++k4) {
    float4 w0 = *(const float4*)&WT[((15 + k4 * 4 + 0) * 256 + u) * 4];
    float4 w1 = *(const float4*)&WT[((15 + k4 * 4 + 1) * 256 + u) * 4];
    float4 w2 = *(const float4*)&WT[((15 + k4 * 4 + 2) * 256 + u) * 4];
    float4 w3 = *(const float4*)&WT[((15 + k4 * 4 + 3) * 256 + u) * 4];
#pragma unroll
    for (int r = 0; r < 16; ++r) {
      float4 xv = *(const float4*)&los[(r0 + r) * 256 + k4 * 4];
      fma_gates(acc[r], xv, w0, w1, w2, w3);
    }
  }
  for (int k4 = 0; k4 < 64; ++k4) {
    float4 w0 = *(const float4*)&WT[((271 + k4 * 4 + 0) * 256 + u) * 4];
    float4 w1 = *(const float4*)&WT[((271 + k4 * 4 + 1) * 256 + u) * 4];
    float4 w2 = *(const float4*)&WT[((271 + k4 * 4 + 2) * 256 + u) * 4];
    float4 w3 = *(const float4*)&WT[((271 + k4 * 4 + 3) * 256 + u) * 4];
#pragma unroll
    for (int r = 0; r < 16; ++r) {
      float4 xv = *(const float4*)&sos[(r0 + r) * 256 + k4 * 4];
      fma_gates(acc[r], xv, w0, w1, w2, w3);
    }
  }
#pragma unroll
  for (int r = 0; r < 16; ++r)
    *(float4*)&gx[(rowbase + r0 + r) * 1024 + u * 4] = acc[r];
}

// ---------- level L-1: h2=c2=0, cell directly from gx ----------
__global__ void k_level_first(const float* __restrict__ gxl,
                              float* __restrict__ h, float* __restrict__ c) {
  size_t idx = (size_t)blockIdx.x * 256 + threadIdx.x;  // < N*256
  float4 g = *(const float4*)&gxl[idx * 4];
  float cn = sigf(g.x) * tanhf(g.z);
  h[idx] = sigf(g.w) * tanhf(cn);
  c[idx] = cn;
}

// ---------- one tree level: gather children, recurrent GEMM (K=256), cell ----------
__global__ __launch_bounds__(256) void k_level(
    const float* __restrict__ gxl, const int* __restrict__ map,
    const float* __restrict__ hprev, const float* __restrict__ cprev,
    const float* __restrict__ WT,   // [256][256][4]
    float* __restrict__ hnext, float* __restrict__ cnext)
{
  __shared__ float h2s[8 * 256];
  __shared__ int ms[16];
  const int rowbase = blockIdx.x * 8;
  const int t = threadIdx.x;
  const int u = t;
  if (t < 16) ms[t] = map[rowbase * 2 + t];
  __syncthreads();
  for (int i = t; i < 8 * 256; i += 256) {
    int r = i >> 8, k = i & 255;
    int a = ms[r * 2], b = ms[r * 2 + 1];
    float v = (a ? hprev[(size_t)(a - 1) * 256 + k] : 0.f)
            + (b ? hprev[(size_t)(b - 1) * 256 + k] : 0.f);
    h2s[i] = 0.5f * v;
  }
  __syncthreads();
  float4 acc[8];
  float c2[8];
#pragma unroll
  for (int r = 0; r < 8; ++r) {
    int a = ms[r * 2], b = ms[r * 2 + 1];
    c2[r] = 0.5f * ((a ? cprev[(size_t)(a - 1) * 256 + u] : 0.f)
                  + (b ? cprev[(size_t)(b - 1) * 256 + u] : 0.f));
    acc[r] = *(const float4*)&gxl[(size_t)(rowbase + r) * 1024 + u * 4];
  }
  for (int k4 = 0; k4 < 64; ++k4) {
    float4 w0 = *(const float4*)&WT[((k4 * 4 + 0) * 256 + u) * 4];
    float4 w1 = *(const float4*)&WT[((k4 * 4 + 1) * 256 + u) * 4];
    float4 w2 = *(const float4*)&WT[((k4 * 4 + 2) * 256 + u) * 4];
    float4 w3 = *(const float4*)&WT[((k4 * 4 + 3) * 256 + u) * 4];
#pragma unroll
    for (int r = 0; r < 8; ++r) {
      float4 xv = *(const float4*)&h2s[r * 256 + k4 * 4];
      fma_gates(acc[r], xv, w0, w1, w2, w3);
    }
  }
#pragma unroll
  for (int r = 0; r < 8; ++r) {
    float cn = sigf(acc[r].y) * c2[r] + sigf(acc[r].x) * tanhf(acc[r].z);
    hnext[(size_t)(rowbase + r) * 256 + u] = sigf(acc[r].w) * tanhf(cn);
    cnext[(size_t)(rowbase + r) * 256 + u] = cn;
  }
}

// ---------- head GEMM (optional BN on input, ReLU out) ----------
__global__ __launch_bounds__(256) void k_head(
    const float* __restrict__ A, const float* __restrict__ WT, const float* __restrict__ bias,
    float* __restrict__ out,
    const float* __restrict__ s1, const float* __restrict__ s2,
    const float* __restrict__ bg, const float* __restrict__ bb, float invM)
{
  __shared__ float as[16 * 256];
  const size_t rowbase = (size_t)blockIdx.x * 16;
  const int t = threadIdx.x; const int u = t;
  for (int i = t; i < 16 * 256; i += 256) {
    float v = A[rowbase * 256 + i];
    if (s1) {
      int f = i & 255;
      float m = s1[f] * invM;
      float var = s2[f] * invM - m * m;
      v = (v - m) * rsqrtf(var + 1e-5f) * bg[f] + bb[f];
    }
    as[i] = v;
  }
  __syncthreads();
  float acc[16];
#pragma unroll
  for (int r = 0; r < 16; ++r) acc[r] = 0.f;
  for (int k4 = 0; k4 < 64; ++k4) {
    float w0 = WT[(k4 * 4 + 0) * 256 + u];
    float w1 = WT[(k4 * 4 + 1) * 256 + u];
    float w2 = WT[(k4 * 4 + 2) * 256 + u];
    float w3 = WT[(k4 * 4 + 3) * 256 + u];
#pragma unroll
    for (int r = 0; r < 16; ++r) {
      float4 xv = *(const float4*)&as[r * 256 + k4 * 4];
      acc[r] = fmaf(xv.x, w0, fmaf(xv.y, w1, fmaf(xv.z, w2, fmaf(xv.w, w3, acc[r]))));
    }
  }
#pragma unroll
  for (int r = 0; r < 16; ++r)
    out[(rowbase + r) * 256 + u] = fmaxf(acc[r] + bias[u], 0.f);
}

// ---------- final sigmoid dot-product, written to 3 output slots ----------
__global__ void k_head_out(const float* __restrict__ Y, const float* __restrict__ Wo,
                           const float* __restrict__ bo,
                           float* __restrict__ d0, float* __restrict__ d1, float* __restrict__ d2)
{
  int row = blockIdx.x * 256 + threadIdx.x;
  if (row >= N_) return;
  float s = 0.f;
  for (int k = 0; k < 256; ++k) s = fmaf(Y[(size_t)row * 256 + k], Wo[k], s);
  float o = sigf(s + bo[0]);
  d0[row] = o; d1[row] = o; d2[row] = o;
}

extern "C" void kernel_launch(void* const* d_in, const int* in_sizes, int n_in,
                              void* d_out, int out_size, void* d_ws, size_t ws_size,
                              hipStream_t stream)
{
  (void)in_sizes; (void)n_in; (void)out_size; (void)ws_size;
  const float* ops     = (const float*)d_in[0];
  const float* cond1   = (const float*)d_in[2];
  const float* cond2   = (const float*)d_in[3];
  const float* smp     = (const float*)d_in[4];
  const float* mask    = (const float*)d_in[5];
  const int*   mapping = (const int*)d_in[6];
  const float* W_ih1 = (const float*)d_in[7];
  const float* W_hh1 = (const float*)d_in[8];
  const float* b_ih1 = (const float*)d_in[9];
  const float* b_hh1 = (const float*)d_in[10];
  const float* W_ih2 = (const float*)d_in[11];
  const float* W_hh2 = (const float*)d_in[12];
  const float* b_ih2 = (const float*)d_in[13];
  const float* b_hh2 = (const float*)d_in[14];
  const float* cond_W = (const float*)d_in[15];
  const float* cond_b = (const float*)d_in[16];
  const float* samp_W = (const float*)d_in[17];
  const float* samp_b = (const float*)d_in[18];
  const float* bn1_g = (const float*)d_in[19];
  const float* bn1_b = (const float*)d_in[20];
  const float* bn2_g = (const float*)d_in[21];
  const float* bn2_b = (const float*)d_in[22];
  const float* bn3_g = (const float*)d_in[23];
  const float* bn3_b = (const float*)d_in[24];
  const float* hW2[2] = {(const float*)d_in[25], (const float*)d_in[31]};
  const float* hb2[2] = {(const float*)d_in[26], (const float*)d_in[32]};
  const float* hW3[2] = {(const float*)d_in[27], (const float*)d_in[33]};
  const float* hb3[2] = {(const float*)d_in[28], (const float*)d_in[34]};
  const float* hWo[2] = {(const float*)d_in[29], (const float*)d_in[35]};
  const float* hbo[2] = {(const float*)d_in[30], (const float*)d_in[36]};
  float* out = (float*)d_out;
  float* ws = (float*)d_ws;

  // workspace layout (floats, 256B-aligned blocks). Total ~224 MB.
  size_t p = 0;
  auto alloc = [&](size_t n) { size_t r = p; p += (n + 63) & ~(size_t)63; return r; };
  float* WihPf  = ws + alloc(64 * 1024 / 2);        // packed bf16, 65536 shorts
  float* WhhPf  = ws + alloc(256 * 1024 / 2);       // packed bf16, 262144 shorts
  float* Wih2T  = ws + alloc((size_t)527 * 1024);
  float* Whh2T  = ws + alloc(256 * 1024);
  float* condWT = ws + alloc(256 * 256);
  float* sampWT = ws + alloc(1000 * 256);
  float* w2T0 = ws + alloc(256 * 256);
  float* w3T0 = ws + alloc(256 * 256);
  float* w2T1 = ws + alloc(256 * 256);
  float* w3T1 = ws + alloc(256 * 256);
  float* s1a = ws + alloc(256); float* s2a = ws + alloc(256);
  float* s1b = ws + alloc(256); float* s2b = ws + alloc(256);
  float* s1c = ws + alloc(256); float* s2c = ws + alloc(256);
  float* z  = ws + alloc((size_t)N_ * 256);
  float* yA = ws + alloc((size_t)N_ * 256);
  float* yB = ws + alloc((size_t)N_ * 256);
  float* hA = ws + alloc((size_t)N_ * 256);
  float* cA = ws + alloc((size_t)N_ * 256);
  float* hB = ws + alloc((size_t)N_ * 256);
  float* cB = ws + alloc((size_t)N_ * 256);
  float* lo = ws + alloc((size_t)LN_ * 256);
  float* so = ws + alloc((size_t)LN_ * 256);
  float* gx = ws + alloc((size_t)LN_ * 1024);
  float* h1 = gx;                       // h1/h2 live only until k_lo; gx reuses region
  float* h2 = gx + (size_t)LN_ * 256;
  short* WihP = (short*)WihPf;
  short* WhhP = (short*)WhhPf;

  const float* w2T[2] = {w2T0, w2T1};
  const float* w3T[2] = {w3T0, w3T1};

  // --- weight transforms (one-shot, tiny) ---
  k_pack_gates<<<(1024 * 64) / 256, 256, 0, stream>>>(W_ih1, WihP, 64);
  k_pack_gates<<<(1024 * 256) / 256, 256, 0, stream>>>(W_hh1, WhhP, 256);
  k_tr_gates<<<(527 * 1024 + 255) / 256, 256, 0, stream>>>(W_ih2, Wih2T, 527);
  k_tr_gates<<<(256 * 1024) / 256, 256, 0, stream>>>(W_hh2, Whh2T, 256);
  k_tr_plain<<<256, 256, 0, stream>>>(cond_W, condWT, 256);
  k_tr_plain<<<1000, 256, 0, stream>>>(samp_W, sampWT, 1000);
  k_tr_plain<<<256, 256, 0, stream>>>(hW2[0], w2T0, 256);
  k_tr_plain<<<256, 256, 0, stream>>>(hW3[0], w3T0, 256);
  k_tr_plain<<<256, 256, 0, stream>>>(hW2[1], w2T1, 256);
  k_tr_plain<<<256, 256, 0, stream>>>(hW3[1], w3T1, 256);

  // --- stage A: shared lstm1 via MFMA over both condition tensors ---
  k_lstm1_mfma<<<1024, 1024, 0, stream>>>(cond1, cond2, WihP, WhhP, b_ih1, b_hh1, h1, h2);

  // --- stage B: lo = bn1( 0.5*(relu(h1@Wc+b)+relu(h2@Wc+b)) ) ---
  k_lo<<<512, 512, 0, stream>>>(h1, h2, condWT, cond_b, lo);
  k_colstats<<<256, 256, 0, stream>>>(lo, LN_, s1a, s2a);
  k_bnapply<<<(LN_ * 256) / 256, 256, 0, stream>>>(lo, lo, s1a, s2a, bn1_g, bn1_b, 1.f / LN_, LN_ * 256);

  // --- stage C: sample encoder ---
  k_samp<<<LN_ / 16, 256, 0, stream>>>(smp, sampWT, samp_b, mask, so);

  // --- stage D: level-parallel x-part of lstm2 (biases folded in) ---
  k_gx<<<LN_ / 32, 512, 0, stream>>>(ops, lo, so, Wih2T, b_ih2, b_hh2, gx);

  // --- stage E: sequential tree recurrence ---
  k_level_first<<<(N_ * 256) / 256, 256, 0, stream>>>(gx + (size_t)15 * N_ * 1024, hA, cA);
  float* hc = hA; float* cc = cA; float* hn = hB; float* cn = cB;
  for (int l = 14; l >= 0; --l) {
    k_level<<<N_ / 8, 256, 0, stream>>>(gx + (size_t)l * N_ * 1024,
                                        mapping + (size_t)l * N_ * 2,
                                        hc, cc, Whh2T, hn, cn);
    float* tp;
    tp = hc; hc = hn; hn = tp;
    tp = cc; cc = cn; cn = tp;
  }

  // --- stage F: heads ---
  k_colstats<<<256, 256, 0, stream>>>(hc, N_, s1b, s2b);
  k_bnapply<<<(N_ * 256) / 256, 256, 0, stream>>>(hc, z, s1b, s2b, bn2_g, bn2_b, 1.f / N_, N_ * 256);
  for (int hd = 0; hd < 2; ++hd) {
    k_head<<<N_ / 16, 256, 0, stream>>>(z, w2T[hd], hb2[hd], yA,
                                        nullptr, nullptr, nullptr, nullptr, 0.f);
    k_colstats<<<256, 256, 0, stream>>>(yA, N_, s1c, s2c);
    k_head<<<N_ / 16, 256, 0, stream>>>(yA, w3T[hd], hb3[hd], yB,
                                        s1c, s2c, bn3_g, bn3_b, 1.f / N_);
    // output layout: o1 | o2 | task1(=o1,o1) | task2(=o2,o2)
    float* o0  = out + (hd == 0 ? 0 : N_);
    float* o1p = out + (hd == 0 ? 2 * N_ : 4 * N_);
    float* o2p = out + (hd == 0 ? 3 * N_ : 5 * N_);
    k_head_out<<<N_ / 256, 256, 0, stream>>>(yB, hWo[hd], hbo[hd], o0, o1p, o2p);
  }
}